// Round 4
// baseline (410.171 us; speedup 1.0000x reference)
//
#include <hip/hip_runtime.h>
#include <hip/hip_bf16.h>

// Problem constants (fixed by setup_inputs)
#define T_SZ 32
#define B_SZ 512
#define F_SZ 2048
#define H_SZ 2048
#define M_SZ (T_SZ * B_SZ)   // 16384 GEMM rows

// GEMM tile config: BM=128, BN=256, BK=64; 4 waves, wave tile 64x128 (2x4 of 32x32x64)
#define BM 128
#define BN 256
#define BK 64

typedef int   i32x8  __attribute__((ext_vector_type(8)));    // 32 fp8 = 8 VGPRs (MFMA A/B frag)
typedef float f32x16 __attribute__((ext_vector_type(16)));   // 32x32 MFMA C/D frag
typedef unsigned short u16x8 __attribute__((ext_vector_type(8)));

__device__ __forceinline__ void gload_lds16(const void* g, void* l) {
    // async global->LDS, 16 B/lane (global_load_lds_dwordx4).
    // LDS dest is wave-uniform base + lane*16; we permute the SOURCE address
    // per lane to implement the bank swizzle.
    __builtin_amdgcn_global_load_lds(
        (const __attribute__((address_space(1))) unsigned int*)g,
        (__attribute__((address_space(3))) unsigned int*)l,
        16, 0, 0);
}

__device__ __forceinline__ float bf16_bits_to_f32(unsigned short u) {
    return __uint_as_float(((unsigned)u) << 16);
}

// ---------------- fp32 -> fp8 e4m3 (OCP), 8 elems/thread, optional pre-scale ----------------
__global__ __launch_bounds__(256) void cvt_fp8_kernel(const float* __restrict__ in,
                                                      unsigned int* __restrict__ out,
                                                      float scale, int n8) {
    int i = blockIdx.x * 256 + threadIdx.x;
    if (i >= n8) return;
    float4 v0 = ((const float4*)in)[2 * i];
    float4 v1 = ((const float4*)in)[2 * i + 1];
    int w0 = __builtin_amdgcn_cvt_pk_fp8_f32(v0.x * scale, v0.y * scale, 0, false);
    w0     = __builtin_amdgcn_cvt_pk_fp8_f32(v0.z * scale, v0.w * scale, w0, true);
    int w1 = __builtin_amdgcn_cvt_pk_fp8_f32(v1.x * scale, v1.y * scale, 0, false);
    w1     = __builtin_amdgcn_cvt_pk_fp8_f32(v1.z * scale, v1.w * scale, w1, true);
    ((uint2*)out)[i] = make_uint2((unsigned)w0, (unsigned)w1);
}

// ---------------- GEMM (MX-fp8): C[m,n] = (1/256) * sum_k A8[m,k]*B8[n,k] + bias[n] ----------------
// BM=128 x BN=256 block, BK=64, 4 waves (2x2), each wave 64x128 = 2x4 tiles of 32x32x64
// (unity e8m0 scales). XOR swizzle of 16B units within each 64B LDS row:
// phys_u = log_u ^ ((row>>1)&3) balances frag ds_read_b128 across banks.
__global__ __launch_bounds__(256) void gemm_fp8_kernel(const unsigned char* __restrict__ A,   // [M_SZ, F_SZ] fp8
                                                       const unsigned char* __restrict__ Bt,  // [H_SZ, F_SZ] fp8 (x256)
                                                       const float* __restrict__ bias,        // [H_SZ]
                                                       __hip_bfloat16* __restrict__ C)        // [M_SZ, H_SZ] bf16
{
    __shared__ __align__(16) unsigned char As[BM * BK];  // 8 KB
    __shared__ __align__(16) unsigned char Bs[BN * BK];  // 16 KB

    const int tid  = threadIdx.x;
    const int lane = tid & 63;
    const int wave = tid >> 6;
    const int wm   = wave >> 1;          // 0..1 -> 64-row half
    const int wn   = wave & 1;           // 0..1 -> 128-col half
    const int m0   = blockIdx.y * BM;
    const int n0   = blockIdx.x * BN;
    const int l31  = lane & 31;
    const int kh   = lane >> 5;          // k-half: frag covers k bytes [kh*32, kh*32+32)

    f32x16 acc[2][4] = {};

    for (int k0 = 0; k0 < F_SZ; k0 += BK) {
        __syncthreads();
        // A: 512 x 16B chunks, B: 1024 x 16B chunks
        #pragma unroll
        for (int j = 0; j < 2; ++j) {
            int c   = j * 256 + tid;
            int row = c >> 2;                     // 0..127
            int u   = (c & 3) ^ ((row >> 1) & 3); // logical 16B unit for phys slot c&3
            gload_lds16(A + (size_t)(m0 + row) * F_SZ + k0 + u * 16, (void*)(As + c * 16));
        }
        #pragma unroll
        for (int j = 0; j < 4; ++j) {
            int c   = j * 256 + tid;
            int row = c >> 2;                     // 0..255
            int u   = (c & 3) ^ ((row >> 1) & 3);
            gload_lds16(Bt + (size_t)(n0 + row) * F_SZ + k0 + u * 16, (void*)(Bs + c * 16));
        }
        __syncthreads();

        i32x8 af[2], bq[4];
        #pragma unroll
        for (int i = 0; i < 2; ++i) {
            const int ra = wm * 64 + i * 32 + l31;
            const int sa = (ra >> 1) & 3;
            ((int4*)&af[i])[0] = *(const int4*)(As + ra * 64 + (((kh * 2 + 0) ^ sa) * 16));
            ((int4*)&af[i])[1] = *(const int4*)(As + ra * 64 + (((kh * 2 + 1) ^ sa) * 16));
        }
        #pragma unroll
        for (int i = 0; i < 4; ++i) {
            const int rb = wn * 128 + i * 32 + l31;
            const int sb = (rb >> 1) & 3;
            ((int4*)&bq[i])[0] = *(const int4*)(Bs + rb * 64 + (((kh * 2 + 0) ^ sb) * 16));
            ((int4*)&bq[i])[1] = *(const int4*)(Bs + rb * 64 + (((kh * 2 + 1) ^ sb) * 16));
        }
        #pragma unroll
        for (int mi = 0; mi < 2; ++mi)
            #pragma unroll
            for (int ni = 0; ni < 4; ++ni)
                acc[mi][ni] = __builtin_amdgcn_mfma_scale_f32_32x32x64_f8f6f4(
                    af[mi], bq[ni], acc[mi][ni],
                    0 /*A fmt e4m3*/, 0 /*B fmt e4m3*/,
                    0, 0x7f7f7f7f,   /* opsel_a, scale_a = 2^0 */
                    0, 0x7f7f7f7f);  /* opsel_b, scale_b = 2^0 */
    }

    // epilogue: 32x32 C/D layout col=lane&31, row=(r&3)+8*(r>>2)+4*(lane>>5)  (m74/m101-verified)
    #pragma unroll
    for (int ni = 0; ni < 4; ++ni) {
        const int gn = n0 + wn * 128 + ni * 32 + l31;
        const float bv = bias[gn];
        #pragma unroll
        for (int mi = 0; mi < 2; ++mi) {
            const int gmb = m0 + wm * 64 + mi * 32 + 4 * kh;
            #pragma unroll
            for (int r = 0; r < 16; ++r) {
                const int grow = gmb + (r & 3) + 8 * (r >> 2);
                C[(size_t)grow * H_SZ + gn] = __float2bfloat16(acc[mi][ni][r] * (1.0f / 256.0f) + bv);
            }
        }
    }
}

// ---------------- row sum-of-squares -> 1/norm table ----------------
// One wave per row of cur [M_SZ, H_SZ]; 4 waves per block.
__global__ __launch_bounds__(256) void row_ss_kernel(const __hip_bfloat16* __restrict__ cur,
                                                     float* __restrict__ ninv) {
    const int lane = threadIdx.x & 63;
    const int row  = blockIdx.x * 4 + (threadIdx.x >> 6);
    const __hip_bfloat16* rp = cur + (size_t)row * H_SZ;

    float s = 0.f;
    #pragma unroll
    for (int i = 0; i < 4; ++i) {                       // 4 x 512 elems per wave
        const u16x8 pk = *(const u16x8*)(rp + i * 512 + lane * 8);
        #pragma unroll
        for (int j = 0; j < 8; ++j) {
            float f = bf16_bits_to_f32(pk[j]);
            s += f * f;
        }
    }
    #pragma unroll
    for (int off = 32; off >= 1; off >>= 1) s += __shfl_down(s, off, 64);
    if (lane == 0) ninv[row] = 1.0f / fmaxf(sqrtf(s), 1e-12f);
}

// ---------------- LIF scan: 4 columns/thread, no barriers ----------------
__global__ __launch_bounds__(256) void lif_scan_kernel(const __hip_bfloat16* __restrict__ cur, // [M_SZ, H_SZ]
                                                       const float* __restrict__ ninv,         // [M_SZ]
                                                       float* __restrict__ spk,                // [T,B,H]
                                                       float* __restrict__ cnt)                // [B,H]
{
    const int gid = blockIdx.x * 256 + threadIdx.x;     // 262144 threads
    const int b   = gid >> 9;                           // 512 col-quads per batch row
    const int h0  = (gid & 511) * 4;

    float v[4]  = {0, 0, 0, 0};
    float cn[4] = {0, 0, 0, 0};
    #pragma unroll
    for (int t = 0; t < T_SZ; ++t) {
        const size_t off = (size_t)(t * B_SZ + b) * H_SZ + h0;
        const ushort4 pk = *(const ushort4*)(cur + off);
        const float inv  = ninv[t * B_SZ + b];          // wave-uniform -> scalar load
        float so[4];
        {
            float c;
            c = bf16_bits_to_f32(pk.x) * inv; v[0] += (c - v[0]) * 0.5f;
            c = bf16_bits_to_f32(pk.y) * inv; v[1] += (c - v[1]) * 0.5f;
            c = bf16_bits_to_f32(pk.z) * inv; v[2] += (c - v[2]) * 0.5f;
            c = bf16_bits_to_f32(pk.w) * inv; v[3] += (c - v[3]) * 0.5f;
        }
        #pragma unroll
        for (int j = 0; j < 4; ++j) {
            float s = (v[j] >= 1.0f) ? 1.0f : 0.0f;     // Heaviside(v - v_th)
            so[j] = s;
            cn[j] += s;
            v[j] = (s != 0.f) ? 0.f : v[j];             // hard reset, detach
        }
        *(float4*)(spk + off) = make_float4(so[0], so[1], so[2], so[3]);
    }
    *(float4*)(cnt + (size_t)b * H_SZ + h0) = make_float4(cn[0], cn[1], cn[2], cn[3]);
}

extern "C" void kernel_launch(void* const* d_in, const int* in_sizes, int n_in,
                              void* d_out, int out_size, void* d_ws, size_t ws_size,
                              hipStream_t stream) {
    const float* x    = (const float*)d_in[0];   // [T,B,F] fp32
    const float* W    = (const float*)d_in[1];   // [H,F]  fp32
    const float* bias = (const float*)d_in[2];   // [H]    fp32

    float* spk = (float*)d_out;                          // [T,B,H]
    float* cnt = spk + (size_t)T_SZ * B_SZ * H_SZ;       // [B,H]

    char* ws = (char*)d_ws;
    unsigned char* x8    = (unsigned char*)ws;                                   // 33.5 MB
    unsigned char* W8    = x8 + (size_t)M_SZ * F_SZ;                             // 4.2 MB
    __hip_bfloat16* curb = (__hip_bfloat16*)(W8 + (size_t)H_SZ * F_SZ);          // 67.1 MB
    float* ninv          = (float*)((char*)curb + (size_t)M_SZ * H_SZ * 2);      // 64 KB

    cvt_fp8_kernel<<<(M_SZ * F_SZ / 8) / 256, 256, 0, stream>>>(x, (unsigned int*)x8, 1.0f,   M_SZ * F_SZ / 8);
    cvt_fp8_kernel<<<(H_SZ * F_SZ / 8) / 256, 256, 0, stream>>>(W, (unsigned int*)W8, 256.0f, H_SZ * F_SZ / 8);
    gemm_fp8_kernel<<<dim3(H_SZ / BN, M_SZ / BM), 256, 0, stream>>>(x8, W8, bias, curb);
    row_ss_kernel<<<M_SZ / 4, 256, 0, stream>>>(curb, ninv);
    lif_scan_kernel<<<(B_SZ * H_SZ / 4) / 256, 256, 0, stream>>>(curb, ninv, spk, cnt);
}

// Round 5
// 352.597 us; speedup vs baseline: 1.1633x; 1.1633x over previous
//
#include <hip/hip_runtime.h>
#include <hip/hip_bf16.h>

// Problem constants (fixed by setup_inputs)
#define T_SZ 32
#define B_SZ 512
#define F_SZ 2048
#define H_SZ 2048
#define M_SZ (T_SZ * B_SZ)   // 16384 GEMM rows

// GEMM tile: BM=BN=128, BK=128 (two 32x32x64 k-steps per staged tile), 4 waves 2x2,
// wave tile 64x64 = 2x2 MFMA tiles -> acc = 64 AGPR (round-4 lesson: 128-acc tiles
// blow the unified VGPR+AGPR budget -> 1 wave/SIMD cliff).
#define BM 128
#define BN 128
#define BK 128

typedef int   i32x8  __attribute__((ext_vector_type(8)));    // 32 fp8 = 8 VGPRs (MFMA A/B frag)
typedef float f32x16 __attribute__((ext_vector_type(16)));   // 32x32 MFMA C/D frag
typedef unsigned short u16x8 __attribute__((ext_vector_type(8)));

__device__ __forceinline__ void gload_lds16(const void* g, void* l) {
    // async global->LDS, 16 B/lane (global_load_lds_dwordx4).
    // LDS dest is wave-uniform base + lane*16; we permute the SOURCE address
    // per lane to implement the bank swizzle.
    __builtin_amdgcn_global_load_lds(
        (const __attribute__((address_space(1))) unsigned int*)g,
        (__attribute__((address_space(3))) unsigned int*)l,
        16, 0, 0);
}

__device__ __forceinline__ float bf16_bits_to_f32(unsigned short u) {
    return __uint_as_float(((unsigned)u) << 16);
}

// ---------------- fp32 -> fp8 e4m3 (OCP), 8 elems/thread, optional pre-scale ----------------
__global__ __launch_bounds__(256) void cvt_fp8_kernel(const float* __restrict__ in,
                                                      unsigned int* __restrict__ out,
                                                      float scale, int n8) {
    int i = blockIdx.x * 256 + threadIdx.x;
    if (i >= n8) return;
    float4 v0 = ((const float4*)in)[2 * i];
    float4 v1 = ((const float4*)in)[2 * i + 1];
    int w0 = __builtin_amdgcn_cvt_pk_fp8_f32(v0.x * scale, v0.y * scale, 0, false);
    w0     = __builtin_amdgcn_cvt_pk_fp8_f32(v0.z * scale, v0.w * scale, w0, true);
    int w1 = __builtin_amdgcn_cvt_pk_fp8_f32(v1.x * scale, v1.y * scale, 0, false);
    w1     = __builtin_amdgcn_cvt_pk_fp8_f32(v1.z * scale, v1.w * scale, w1, true);
    ((uint2*)out)[i] = make_uint2((unsigned)w0, (unsigned)w1);
}

// ---------------- zero the row sum-of-squares accumulator (ws is poisoned 0xAA) ----------------
__global__ __launch_bounds__(256) void init_ss_kernel(float4* __restrict__ ss4) {
    ss4[blockIdx.x * 256 + threadIdx.x] = make_float4(0.f, 0.f, 0.f, 0.f);
}

// ---------------- GEMM (MX-fp8) + fused row-SS ----------------
// C[m,n] = (1/256) * sum_k A8[m,k]*B8[n,k] + bias[n];  ss[m] += sum_n C[m,n]^2 (atomic)
// 128x128 block, BK=128 (2 k-steps of 32x32x64, unity e8m0 scales), 16 barriers total.
// LDS rows are 128 B = 8 x 16B units; XOR swizzle phys_u = log_u ^ (row&7) spreads
// frag ds_read_b128 uniformly over banks.
__global__ __launch_bounds__(256, 3) void gemm_fp8_kernel(const unsigned char* __restrict__ A,   // [M_SZ,F_SZ] fp8
                                                          const unsigned char* __restrict__ Bt,  // [H_SZ,F_SZ] fp8 (x256)
                                                          const float* __restrict__ bias,        // [H_SZ]
                                                          __hip_bfloat16* __restrict__ C,        // [M_SZ,H_SZ] bf16
                                                          float* __restrict__ ss)                // [M_SZ] atomic SS
{
    __shared__ __align__(16) unsigned char As[BM * BK];  // 16 KB
    __shared__ __align__(16) unsigned char Bs[BN * BK];  // 16 KB

    const int tid  = threadIdx.x;
    const int lane = tid & 63;
    const int wave = tid >> 6;
    const int wm   = wave >> 1;          // 0..1 -> 64-row half
    const int wn   = wave & 1;           // 0..1 -> 64-col half
    const int m0   = blockIdx.y * BM;
    const int n0   = blockIdx.x * BN;
    const int l31  = lane & 31;
    const int kh   = lane >> 5;          // k-half within a 64B MFMA slice

    f32x16 acc[2][2] = {};

    for (int k0 = 0; k0 < F_SZ; k0 += BK) {
        __syncthreads();
        #pragma unroll
        for (int j = 0; j < 4; ++j) {                  // A: 1024 x 16B chunks
            int c   = j * 256 + tid;
            int row = c >> 3;                          // 0..127
            int u   = (c & 7) ^ (row & 7);             // logical unit feeding phys slot c&7
            gload_lds16(A + (size_t)(m0 + row) * F_SZ + k0 + u * 16, (void*)(As + c * 16));
        }
        #pragma unroll
        for (int j = 0; j < 4; ++j) {                  // B: 1024 x 16B chunks
            int c   = j * 256 + tid;
            int row = c >> 3;
            int u   = (c & 7) ^ (row & 7);
            gload_lds16(Bt + (size_t)(n0 + row) * F_SZ + k0 + u * 16, (void*)(Bs + c * 16));
        }
        __syncthreads();

        #pragma unroll
        for (int s = 0; s < 2; ++s) {                  // two 64B k-steps per staged tile
            i32x8 af[2], bq[2];
            #pragma unroll
            for (int i = 0; i < 2; ++i) {
                const int ra = wm * 64 + i * 32 + l31;
                const int rb = wn * 64 + i * 32 + l31;
                const int ua = s * 4 + kh * 2;
                ((int4*)&af[i])[0] = *(const int4*)(As + ra * BK + (((ua + 0) ^ (ra & 7)) * 16));
                ((int4*)&af[i])[1] = *(const int4*)(As + ra * BK + (((ua + 1) ^ (ra & 7)) * 16));
                ((int4*)&bq[i])[0] = *(const int4*)(Bs + rb * BK + (((ua + 0) ^ (rb & 7)) * 16));
                ((int4*)&bq[i])[1] = *(const int4*)(Bs + rb * BK + (((ua + 1) ^ (rb & 7)) * 16));
            }
            #pragma unroll
            for (int mi = 0; mi < 2; ++mi)
                #pragma unroll
                for (int ni = 0; ni < 2; ++ni)
                    acc[mi][ni] = __builtin_amdgcn_mfma_scale_f32_32x32x64_f8f6f4(
                        af[mi], bq[ni], acc[mi][ni],
                        0 /*A fmt e4m3*/, 0 /*B fmt e4m3*/,
                        0, 0x7f7f7f7f,   /* opsel_a, scale_a = 2^0 */
                        0, 0x7f7f7f7f);  /* opsel_b, scale_b = 2^0 */
        }
    }

    // epilogue: 32x32 C/D layout col=lane&31, row=(r&3)+8*(r>>2)+4*(lane>>5)  (m74/m101-verified)
    // Also accumulate per-row sum-of-squares over this block's 128 cols.
    float ssl[2][16];
    #pragma unroll
    for (int ni = 0; ni < 2; ++ni) {
        const int gn = n0 + wn * 64 + ni * 32 + l31;
        const float bv = bias[gn];
        #pragma unroll
        for (int mi = 0; mi < 2; ++mi) {
            const int gmb = m0 + wm * 64 + mi * 32 + 4 * kh;
            #pragma unroll
            for (int r = 0; r < 16; ++r) {
                const int grow = gmb + (r & 3) + 8 * (r >> 2);
                const float val = acc[mi][ni][r] * (1.0f / 256.0f) + bv;
                C[(size_t)grow * H_SZ + gn] = __float2bfloat16(val);
                if (ni == 0) ssl[mi][r] = val * val;
                else         ssl[mi][r] += val * val;
            }
        }
    }
    // cross-lane: sum over the 32 col-lanes (kh halves hold different rows; masks<32 stay in-half)
    #pragma unroll
    for (int mi = 0; mi < 2; ++mi) {
        const int gmb = m0 + wm * 64 + mi * 32 + 4 * kh;
        #pragma unroll
        for (int r = 0; r < 16; ++r) {
            float p = ssl[mi][r];
            p += __shfl_xor(p, 1, 64);
            p += __shfl_xor(p, 2, 64);
            p += __shfl_xor(p, 4, 64);
            p += __shfl_xor(p, 8, 64);
            p += __shfl_xor(p, 16, 64);
            if (l31 == 0)
                atomicAdd(ss + gmb + (r & 3) + 8 * (r >> 2), p);
        }
    }
}

// ---------------- LIF scan: 4 columns/thread, no barriers ----------------
__global__ __launch_bounds__(256) void lif_scan_kernel(const __hip_bfloat16* __restrict__ cur, // [M_SZ,H_SZ]
                                                       const float* __restrict__ ss,           // [M_SZ] sum-of-squares
                                                       float* __restrict__ spk,                // [T,B,H]
                                                       float* __restrict__ cnt)                // [B,H]
{
    const int gid = blockIdx.x * 256 + threadIdx.x;     // 262144 threads
    const int b   = gid >> 9;                           // 512 col-quads per batch row
    const int h0  = (gid & 511) * 4;

    float v[4]  = {0, 0, 0, 0};
    float cn[4] = {0, 0, 0, 0};
    #pragma unroll
    for (int t = 0; t < T_SZ; ++t) {
        const size_t off = (size_t)(t * B_SZ + b) * H_SZ + h0;
        const ushort4 pk = *(const ushort4*)(cur + off);
        const float inv  = 1.0f / fmaxf(sqrtf(ss[t * B_SZ + b]), 1e-12f); // wave-uniform
        float so[4];
        {
            float c;
            c = bf16_bits_to_f32(pk.x) * inv; v[0] += (c - v[0]) * 0.5f;
            c = bf16_bits_to_f32(pk.y) * inv; v[1] += (c - v[1]) * 0.5f;
            c = bf16_bits_to_f32(pk.z) * inv; v[2] += (c - v[2]) * 0.5f;
            c = bf16_bits_to_f32(pk.w) * inv; v[3] += (c - v[3]) * 0.5f;
        }
        #pragma unroll
        for (int j = 0; j < 4; ++j) {
            float s = (v[j] >= 1.0f) ? 1.0f : 0.0f;     // Heaviside(v - v_th)
            so[j] = s;
            cn[j] += s;
            v[j] = (s != 0.f) ? 0.f : v[j];             // hard reset, detach
        }
        *(float4*)(spk + off) = make_float4(so[0], so[1], so[2], so[3]);
    }
    *(float4*)(cnt + (size_t)b * H_SZ + h0) = make_float4(cn[0], cn[1], cn[2], cn[3]);
}

extern "C" void kernel_launch(void* const* d_in, const int* in_sizes, int n_in,
                              void* d_out, int out_size, void* d_ws, size_t ws_size,
                              hipStream_t stream) {
    const float* x    = (const float*)d_in[0];   // [T,B,F] fp32
    const float* W    = (const float*)d_in[1];   // [H,F]  fp32
    const float* bias = (const float*)d_in[2];   // [H]    fp32

    float* spk = (float*)d_out;                          // [T,B,H]
    float* cnt = spk + (size_t)T_SZ * B_SZ * H_SZ;       // [B,H]

    char* ws = (char*)d_ws;
    unsigned char* x8    = (unsigned char*)ws;                                   // 33.5 MB
    unsigned char* W8    = x8 + (size_t)M_SZ * F_SZ;                             // 4.2 MB
    __hip_bfloat16* curb = (__hip_bfloat16*)(W8 + (size_t)H_SZ * F_SZ);          // 67.1 MB
    float* ss            = (float*)((char*)curb + (size_t)M_SZ * H_SZ * 2);      // 64 KB

    init_ss_kernel<<<M_SZ / 1024, 256, 0, stream>>>((float4*)ss);
    cvt_fp8_kernel<<<(M_SZ * F_SZ / 8) / 256, 256, 0, stream>>>(x, (unsigned int*)x8, 1.0f,   M_SZ * F_SZ / 8);
    cvt_fp8_kernel<<<(H_SZ * F_SZ / 8) / 256, 256, 0, stream>>>(W, (unsigned int*)W8, 256.0f, H_SZ * F_SZ / 8);
    gemm_fp8_kernel<<<dim3(H_SZ / BN, M_SZ / BM), 256, 0, stream>>>(x8, W8, bias, curb, ss);
    lif_scan_kernel<<<(B_SZ * H_SZ / 4) / 256, 256, 0, stream>>>(curb, ss, spk, cnt);
}